// Round 4
// baseline (963.150 us; speedup 1.0000x reference)
//
#include <hip/hip_runtime.h>
#include <hip/hip_bf16.h>

#define NNODE 16384

typedef short v8s __attribute__((ext_vector_type(8)));
typedef float v4f __attribute__((ext_vector_type(4)));

__device__ __forceinline__ unsigned short f2bf(float v) {
    unsigned u = __float_as_uint(v);
    unsigned r = (u + 0x7FFF + ((u >> 16) & 1)) >> 16;
    return (unsigned short)r;
}
__device__ __forceinline__ float bf2f(unsigned short s) {
    return __uint_as_float(((unsigned)s) << 16);
}

// ======================= split-bf16 MFMA GEMM v3 (A in LDS, B direct from L2) ==========
// C[16384, Ncol] = epi( A @ B + bias ). A pre-split bf16 planes [16384][ldA].
// B pre-split/transposed [Npad][Kpad], Kpad=ceil64(K), zero-padded (so A cols K..Kpad may
// be garbage). Tile 128x128, 4 waves (2x2), wave tile 64x64. A LDS swizzle (row&7)<<4.
// 3-term split product: Ah*Bh + Al*Bh + Ah*Bl.  OUT: 0 = f32 C, 1 = split bf16 Ch/Cl.
template<int EPI, int OUT>
__global__ __launch_bounds__(256, 3)
void mgemm3(const unsigned short* __restrict__ Ah, const unsigned short* __restrict__ Al,
            int ldA, int K,
            const unsigned short* __restrict__ Bh, const unsigned short* __restrict__ Bl,
            int Kpad,
            float* __restrict__ Cf, unsigned short* __restrict__ Ch, unsigned short* __restrict__ Cl,
            int ldC, int Ncol, const float* __restrict__ bias)
{
    __shared__ __align__(16) unsigned short AhS[128 * 64];
    __shared__ __align__(16) unsigned short AlS[128 * 64];
    const int bm = blockIdx.x * 128;
    const int bn = blockIdx.y * 128;
    const int tid = threadIdx.x;
    const int lane = tid & 63, wid = tid >> 6;
    const int wm = wid >> 1, wn = wid & 1;
    const int r16 = lane & 15, q = lane >> 4;
    v4f acc[4][4];
#pragma unroll
    for (int i = 0; i < 4; i++)
#pragma unroll
        for (int j = 0; j < 4; j++) acc[i][j] = (v4f){0.f, 0.f, 0.f, 0.f};

    // staging constants: per p-iter rows p*32 + (tid>>3), 16B chunk (tid&7)
    const int srB  = tid >> 3;             // 0..31
    const int sgk  = (tid & 7) * 8;        // element offset in row
    const int sbo0 = ((tid & 7) * 16) ^ (((tid >> 3) & 7) << 4);  // swizzled byte off

    const int nK = (K + 63) >> 6;
    for (int s = 0; s < nK; s++) {
        const int k0 = s << 6;
        // ---- stage A tile (both planes), unconditional (B rows >= K are zero) ----
#pragma unroll
        for (int p = 0; p < 4; p++) {
            int row = p * 32 + srB;
            size_t go = (size_t)(bm + row) * ldA + k0 + sgk;
            v8s hv = *(const v8s*)(const void*)(Ah + go);
            v8s lv = *(const v8s*)(const void*)(Al + go);
            int bo = row * 128 + sbo0;
            *(v8s*)(void*)((char*)AhS + bo) = hv;
            *(v8s*)(void*)((char*)AlS + bo) = lv;
        }
        // ---- B fragments straight from global (L2-hot weights) ----
        v8s Bfh[2][4], Bfl[2][4];
#pragma unroll
        for (int kc = 0; kc < 2; kc++)
#pragma unroll
            for (int nf = 0; nf < 4; nf++) {
                int col = bn + wn * 64 + nf * 16 + r16;
                size_t ob = (size_t)col * Kpad + k0 + kc * 32 + q * 8;
                Bfh[kc][nf] = *(const v8s*)(const void*)(Bh + ob);
                Bfl[kc][nf] = *(const v8s*)(const void*)(Bl + ob);
            }
        __syncthreads();
        // ---- compute ----
#pragma unroll
        for (int kc = 0; kc < 2; kc++) {
#pragma unroll
            for (int mf = 0; mf < 4; mf++) {
                int arow = wm * 64 + mf * 16 + r16;
                int ao = arow * 128 + (((kc * 64) + q * 16) ^ ((arow & 7) << 4));
                v8s ah = *(const v8s*)(const void*)((const char*)AhS + ao);
                v8s al = *(const v8s*)(const void*)((const char*)AlS + ao);
#pragma unroll
                for (int nf = 0; nf < 4; nf++) {
                    acc[mf][nf] = __builtin_amdgcn_mfma_f32_16x16x32_bf16(ah, Bfh[kc][nf], acc[mf][nf], 0, 0, 0);
                    acc[mf][nf] = __builtin_amdgcn_mfma_f32_16x16x32_bf16(al, Bfh[kc][nf], acc[mf][nf], 0, 0, 0);
                    acc[mf][nf] = __builtin_amdgcn_mfma_f32_16x16x32_bf16(ah, Bfl[kc][nf], acc[mf][nf], 0, 0, 0);
                }
            }
        }
        __syncthreads();
    }
    // ---- epilogue ----
#pragma unroll
    for (int mf = 0; mf < 4; mf++)
#pragma unroll
        for (int nf = 0; nf < 4; nf++) {
            int col = bn + wn * 64 + nf * 16 + r16;
            if (col < Ncol) {
                float bv = bias ? bias[col] : 0.f;
#pragma unroll
                for (int r = 0; r < 4; r++) {
                    int row = bm + wm * 64 + mf * 16 + q * 4 + r;
                    float v = acc[mf][nf][r] + bv;
                    if (EPI == 1) v = fmaxf(v, 0.f);
                    if (EPI == 2) v = (v > 0.f) ? v : 0.01f * v;
                    size_t o = (size_t)row * ldC + col;
                    if (OUT == 0) {
                        Cf[o] = v;
                    } else {
                        unsigned short h = f2bf(v);
                        Ch[o] = h;
                        Cl[o] = f2bf(v - bf2f(h));
                    }
                }
            }
        }
}

// ======================= weight preps =======================
__global__ void prep_bt(const float* __restrict__ W, unsigned short* __restrict__ Bh,
                        unsigned short* __restrict__ Bl, int K, int N, int Kpad, int Npad)
{
    int idx = blockIdx.x * 256 + threadIdx.x;
    if (idx >= Npad * Kpad) return;
    int n = idx / Kpad, k = idx % Kpad;
    float v = (n < N && k < K) ? W[(size_t)k * N + n] : 0.f;
    unsigned short h = f2bf(v);
    Bh[idx] = h;
    Bl[idx] = f2bf(v - bf2f(h));
}

// Wu fold: source [5cin, cout]; X row layout [h(cin) | sum | max | std] -> K = 4cin
__global__ void prep_wu(const float* __restrict__ Wu, unsigned short* __restrict__ Bh,
                        unsigned short* __restrict__ Bl, int cin, int cout, int Npad)
{
    int Kpad = 4 * cin;
    int idx = blockIdx.x * 256 + threadIdx.x;
    if (idx >= Npad * Kpad) return;
    int n = idx / Kpad, k = idx % Kpad;
    float v = 0.f;
    if (n < cout) {
        int qq = k / cin, r = k - qq * cin;
        if (qq == 0)      v = Wu[(size_t)r * cout + n];
        else if (qq == 1) v = Wu[(size_t)(cin + r) * cout + n] * 0.125f + Wu[(size_t)(3 * cin + r) * cout + n];
        else if (qq == 2) v = Wu[(size_t)(2 * cin + r) * cout + n];
        else              v = Wu[(size_t)(4 * cin + r) * cout + n];
    }
    unsigned short h = f2bf(v);
    Bh[idx] = h;
    Bl[idx] = f2bf(v - bf2f(h));
}

// Wx scaled by BN scale: B[n][k] = Wx[k][n]*scale[k]
__global__ void prep_wx(const float* __restrict__ Wx, const float* __restrict__ scale,
                        unsigned short* __restrict__ Bh, unsigned short* __restrict__ Bl,
                        int K, int N, int Kpad, int Npad)
{
    int idx = blockIdx.x * 256 + threadIdx.x;
    if (idx >= Npad * Kpad) return;
    int n = idx / Kpad, k = idx % Kpad;
    float v = (n < N && k < K) ? Wx[(size_t)k * N + n] * scale[k] : 0.f;
    unsigned short h = f2bf(v);
    Bh[idx] = h;
    Bl[idx] = f2bf(v - bf2f(h));
}

// bias2[n] = bx[n] + sum_k shift[k]*Wx[k][n]   (parallel: one block per n)
__global__ __launch_bounds__(256) void bias2p_k(const float* __restrict__ Wx,
    const float* __restrict__ bx, const float* __restrict__ shift,
    float* __restrict__ bias2, int K, int N)
{
    int n = blockIdx.x, tid = threadIdx.x;
    float s = 0.f;
    for (int k = tid; k < K; k += 256) s = fmaf(shift[k], Wx[(size_t)k * N + n], s);
    __shared__ float red[256];
    red[tid] = s; __syncthreads();
    for (int st = 128; st > 0; st >>= 1) { if (tid < st) red[tid] += red[tid + st]; __syncthreads(); }
    if (tid == 0) bias2[n] = red[0] + bx[n];
}

// Wm bias for H2 columns: [0]*cin ++ bm
__global__ void prep_biasH(const float* __restrict__ bm, float* __restrict__ biasH, int cin)
{
    int i = blockIdx.x * 256 + threadIdx.x;
    if (i < 2 * cin) biasH[i] = (i < cin) ? 0.f : bm[i - cin];
}

// f32 [16384, w] (ld ldS) -> split planes at column offset offX
__global__ void csplit_k(const float* __restrict__ src, int ldS, int w,
                         unsigned short* __restrict__ Xh, unsigned short* __restrict__ Xl,
                         int ldX, int offX)
{
    int idx = blockIdx.x * 256 + threadIdx.x;
    if (idx >= NNODE * w) return;
    int rrow = idx / w, c = idx - rrow * w;
    float v = src[(size_t)rrow * ldS + c];
    unsigned short h = f2bf(v);
    size_t o = (size_t)rrow * ldX + offX + c;
    Xh[o] = h;
    Xl[o] = f2bf(v - bf2f(h));
}

// ======================= fp32 GEMM (small d2 path) =======================
__global__ __launch_bounds__(256)
void gemm_k(const float* __restrict__ A, const float* __restrict__ Bw,
            float* __restrict__ C, int Ncol, int K, const float* __restrict__ bias)
{
    __shared__ float As[16][128];
    __shared__ float Bs[16][64];
    const int bm = blockIdx.y * 128;
    const int bn = blockIdx.x * 64;
    const int tid = threadIdx.x;
    const int tx = tid & 15, ty = tid >> 4;
    float acc[8][4];
#pragma unroll
    for (int i = 0; i < 8; i++)
#pragma unroll
        for (int j = 0; j < 4; j++) acc[i][j] = 0.f;

    for (int k0 = 0; k0 < K; k0 += 16) {
#pragma unroll
        for (int i = 0; i < 2; i++) {
            int idx = tid * 2 + i;
            int row = idx >> 2;
            int k4  = (idx & 3) << 2;
            const float* ap = A + (size_t)(bm + row) * K + k0 + k4;
            float4 v = *reinterpret_cast<const float4*>(ap);
            As[k4 + 0][row] = v.x;
            As[k4 + 1][row] = v.y;
            As[k4 + 2][row] = v.z;
            As[k4 + 3][row] = v.w;
        }
        {
            int row = tid >> 4;
            int c4  = (tid & 15) << 2;
            int gn  = bn + c4;
            float4 v;
            if (gn + 3 < Ncol) {
                v = *reinterpret_cast<const float4*>(Bw + (size_t)(k0 + row) * Ncol + gn);
            } else {
                float t0 = (gn + 0 < Ncol) ? Bw[(size_t)(k0 + row) * Ncol + gn + 0] : 0.f;
                float t1 = (gn + 1 < Ncol) ? Bw[(size_t)(k0 + row) * Ncol + gn + 1] : 0.f;
                float t2 = (gn + 2 < Ncol) ? Bw[(size_t)(k0 + row) * Ncol + gn + 2] : 0.f;
                float t3 = (gn + 3 < Ncol) ? Bw[(size_t)(k0 + row) * Ncol + gn + 3] : 0.f;
                v = make_float4(t0, t1, t2, t3);
            }
            *reinterpret_cast<float4*>(&Bs[row][c4]) = v;
        }
        __syncthreads();
#pragma unroll
        for (int kk = 0; kk < 16; kk++) {
            float a0[8], b0[4];
#pragma unroll
            for (int i = 0; i < 8; i++) a0[i] = As[kk][ty * 8 + i];
#pragma unroll
            for (int j = 0; j < 4; j++) b0[j] = Bs[kk][tx * 4 + j];
#pragma unroll
            for (int i = 0; i < 8; i++)
#pragma unroll
                for (int j = 0; j < 4; j++) acc[i][j] = fmaf(a0[i], b0[j], acc[i][j]);
        }
        __syncthreads();
    }
#pragma unroll
    for (int i = 0; i < 8; i++) {
        int r = bm + ty * 8 + i;
#pragma unroll
        for (int j = 0; j < 4; j++) {
            int c = bn + tx * 4 + j;
            if (c < Ncol) C[(size_t)r * Ncol + c] = acc[i][j] + (bias ? bias[c] : 0.f);
        }
    }
}

// ======================= PNA aggregation (split-bf16 output into X) =======================
__global__ __launch_bounds__(256)
void agg2_k(const float* __restrict__ H2, const float* __restrict__ es,
            const int* __restrict__ src, const float* __restrict__ Wme,
            unsigned short* __restrict__ Xh, unsigned short* __restrict__ Xl,
            int cin, int ldH, int ldX, int offX)
{
    const int g = blockIdx.x;
    const int c0 = blockIdx.y * 64;
    const int qz = blockIdx.z;
    const int tid = threadIdx.x;
    const int nl = tid >> 6, c = tid & 63;
    const int cc = c0 + c;
    const bool act = cc < cin;
    __shared__ float esl[4][128];
    __shared__ int srcl[512];
    {
        int e0 = g * 2048 + qz * 512;
        for (int i = tid; i < 512; i += 256) srcl[i] = src[e0 + i] - g * 256;
    }
    float wreg[16];
#pragma unroll
    for (int j = 0; j < 16; j++) wreg[j] = act ? Wme[j * cin + cc] : 0.f;
    __syncthreads();
    const float* Hsrc = H2 + (size_t)(g * 256) * ldH + c0;
    const float* Hdst = H2 + (size_t)(g * 256) * ldH + cin + c0;
    for (int i = 0; i < 16; i++) {
        const int vl = qz * 64 + i * 4 + nl;
        {
            const float* ep = es + (size_t)(g * 256 + vl) * 128;
            esl[nl][c] = ep[c];
            esl[nl][64 + c] = ep[64 + c];
        }
        __syncthreads();
        if (act) {
            float hd = Hdst[(size_t)vl * ldH + c];
            float sum = 0.f, sq = 0.f, mx = -INFINITY;
#pragma unroll
            for (int e = 0; e < 8; e++) {
                int sl = srcl[(i * 4 + nl) * 8 + e];
                float m = hd + Hsrc[(size_t)sl * ldH + c];
                float4 e0 = *(const float4*)&esl[nl][e * 16 + 0];
                float4 e1 = *(const float4*)&esl[nl][e * 16 + 4];
                float4 e2 = *(const float4*)&esl[nl][e * 16 + 8];
                float4 e3 = *(const float4*)&esl[nl][e * 16 + 12];
                m = fmaf(e0.x, wreg[0], m);  m = fmaf(e0.y, wreg[1], m);
                m = fmaf(e0.z, wreg[2], m);  m = fmaf(e0.w, wreg[3], m);
                m = fmaf(e1.x, wreg[4], m);  m = fmaf(e1.y, wreg[5], m);
                m = fmaf(e1.z, wreg[6], m);  m = fmaf(e1.w, wreg[7], m);
                m = fmaf(e2.x, wreg[8], m);  m = fmaf(e2.y, wreg[9], m);
                m = fmaf(e2.z, wreg[10], m); m = fmaf(e2.w, wreg[11], m);
                m = fmaf(e3.x, wreg[12], m); m = fmaf(e3.y, wreg[13], m);
                m = fmaf(e3.z, wreg[14], m); m = fmaf(e3.w, wreg[15], m);
                sum += m;
                sq = fmaf(m, m, sq);
                mx = fmaxf(mx, m);
            }
            float mean = sum * 0.125f, msq = sq * 0.125f;
            float stdv = sqrtf(fmaxf(msq - mean * mean, 0.f) + 1e-30f);
            size_t o = (size_t)(g * 256 + vl) * ldX + offX + cc;
            unsigned short h;
            h = f2bf(sum);  Xh[o] = h;            Xl[o] = f2bf(sum - bf2f(h));
            h = f2bf(mx);   Xh[o + cin] = h;      Xl[o + cin] = f2bf(mx - bf2f(h));
            h = f2bf(stdv); Xh[o + 2 * cin] = h;  Xl[o + 2 * cin] = f2bf(stdv - bf2f(h));
        }
        __syncthreads();
    }
}

// ======================= BatchNorm stats (deterministic, split-bf16 input) ===========
__global__ void bnstats1s_k(const unsigned short* __restrict__ uh, const unsigned short* __restrict__ ul,
                            float* __restrict__ part, int cout)
{
    int c = threadIdx.x;
    if (c >= cout) return;
    int r0 = blockIdx.x * 256;
    float s = 0.f, q = 0.f;
    for (int r = r0; r < r0 + 256; r++) {
        size_t o = (size_t)r * cout + c;
        float v = bf2f(uh[o]) + bf2f(ul[o]);
        s += v;
        q = fmaf(v, v, q);
    }
    part[(size_t)blockIdx.x * cout + c] = s;
    part[(size_t)(64 + blockIdx.x) * cout + c] = q;
}

__global__ void bnstats2_k(const float* __restrict__ part, const float* __restrict__ bng,
                           const float* __restrict__ bnb, float* __restrict__ scale,
                           float* __restrict__ shift, int cout)
{
    int c = threadIdx.x;
    if (c >= cout) return;
    float s = 0.f, q = 0.f;
    for (int b = 0; b < 64; b++) { s += part[(size_t)b * cout + c]; q += part[(size_t)(64 + b) * cout + c]; }
    float mean = s / 16384.f;
    float var  = q / 16384.f - mean * mean;
    float sc   = bng[c] / sqrtf(var + 1e-5f);
    scale[c] = sc;
    shift[c] = bnb[c] - mean * sc;
}

// ======================= head =======================
__global__ void rowmax_k(const float* __restrict__ h3, float* __restrict__ nm)
{
    int wave = threadIdx.x >> 6;
    int lane = threadIdx.x & 63;
    int node = blockIdx.x * 4 + wave;
    const float* row = h3 + (size_t)node * 192;
    float m = -INFINITY;
    for (int t = lane; t < 192; t += 64) m = fmaxf(m, row[t]);
#pragma unroll
    for (int off = 32; off > 0; off >>= 1) m = fmaxf(m, __shfl_down(m, off, 64));
    if (lane == 0) nm[node] = m;
}

__global__ __launch_bounds__(256) void g_k(const float* __restrict__ nm,
    const float* __restrict__ W3, const float* __restrict__ b3,
    const float* __restrict__ W4, const float* __restrict__ b4,
    float* __restrict__ g)
{
    __shared__ float row[256];
    __shared__ float t1[64];
    int b = blockIdx.x, tid = threadIdx.x;
    row[tid] = nm[b * 256 + tid];
    __syncthreads();
    if (tid < 64) {
        float a = b3[tid];
        for (int k = 0; k < 256; k++) a = fmaf(row[k], W3[k * 64 + tid], a);
        t1[tid] = fmaxf(a, 0.f);
    }
    __syncthreads();
    float a = b4[tid];
    for (int j = 0; j < 64; j++) a = fmaf(t1[j], W4[j * 256 + tid], a);
    g[b * 256 + tid] = 1.f / (1.f + expf(-a));
}

// ======================= masked softmax (parallel, 2-pass) =======================
__global__ __launch_bounds__(256) void sm1_k(const float* __restrict__ mask,
    const float* __restrict__ g, const float* __restrict__ h3, float* __restrict__ part)
{
    int b = blockIdx.x, s = blockIdx.y, tid = threadIdx.x;
    float l[24];
#pragma unroll
    for (int t = 0; t < 24; t++) {
        int i = s * 6144 + t * 256 + tid;
        size_t idx = (size_t)b * 49152 + i;
        float mk = mask[idx];
        l[t] = (mk == 0.f) ? -1e5f : g[b * 256 + i / 192] * h3[idx];
    }
    float m = -INFINITY;
#pragma unroll
    for (int t = 0; t < 24; t++) m = fmaxf(m, l[t]);
    __shared__ float red[256];
    red[tid] = m; __syncthreads();
    for (int st = 128; st > 0; st >>= 1) { if (tid < st) red[tid] = fmaxf(red[tid], red[tid + st]); __syncthreads(); }
    m = red[0]; __syncthreads();
    float z = 0.f;
#pragma unroll
    for (int t = 0; t < 24; t++) z += expf(l[t] - m);
    red[tid] = z; __syncthreads();
    for (int st = 128; st > 0; st >>= 1) { if (tid < st) red[tid] += red[tid + st]; __syncthreads(); }
    if (tid == 0) { part[(b * 8 + s) * 2] = m; part[(b * 8 + s) * 2 + 1] = red[0]; }
}

__global__ void sm2_k(const float* __restrict__ part, float* __restrict__ mz)
{
    int b = threadIdx.x;
    if (b >= 64) return;
    float M = -INFINITY;
    for (int s = 0; s < 8; s++) M = fmaxf(M, part[(b * 8 + s) * 2]);
    float Z = 0.f;
    for (int s = 0; s < 8; s++) Z += part[(b * 8 + s) * 2 + 1] * expf(part[(b * 8 + s) * 2] - M);
    mz[b * 2] = M;
    mz[b * 2 + 1] = 1.f / Z;
}

__global__ __launch_bounds__(256) void sm3_k(const float* __restrict__ mask,
    const float* __restrict__ g, const float* __restrict__ h3,
    const float* __restrict__ mz, float* __restrict__ out)
{
    int b = blockIdx.x, s = blockIdx.y, tid = threadIdx.x;
    float M = mz[b * 2], invZ = mz[b * 2 + 1];
#pragma unroll
    for (int t = 0; t < 24; t++) {
        int i = s * 6144 + t * 256 + tid;
        size_t idx = (size_t)b * 49152 + i;
        float mk = mask[idx];
        float v = (mk == 0.f) ? -1e5f : g[b * 256 + i / 192] * h3[idx];
        out[idx] = expf(v - M) * invZ;
    }
}

// ======================= launcher =======================
extern "C" void kernel_launch(void* const* d_in, const int* in_sizes, int n_in,
                              void* d_out, int out_size, void* d_ws, size_t ws_size,
                              hipStream_t stream)
{
    const float* ns   = (const float*)d_in[0];
    const float* es   = (const float*)d_in[1];
    const float* dm   = (const float*)d_in[2];
    const float* mask = (const float*)d_in[3];
    const int*   src  = (const int*)d_in[4];
    const float* Wm1 = (const float*)d_in[6],  *bm1 = (const float*)d_in[7];
    const float* Wu1 = (const float*)d_in[8],  *bu1 = (const float*)d_in[9];
    const float* bng1= (const float*)d_in[10], *bnb1= (const float*)d_in[11];
    const float* Wx1 = (const float*)d_in[12], *bx1 = (const float*)d_in[13];
    const float* Wm2 = (const float*)d_in[14], *bm2 = (const float*)d_in[15];
    const float* Wu2 = (const float*)d_in[16], *bu2 = (const float*)d_in[17];
    const float* bng2= (const float*)d_in[18], *bnb2= (const float*)d_in[19];
    const float* Wx2 = (const float*)d_in[20], *bx2 = (const float*)d_in[21];
    const float* Wm3 = (const float*)d_in[22], *bm3 = (const float*)d_in[23];
    const float* Wu3 = (const float*)d_in[24], *bu3 = (const float*)d_in[25];
    const float* bng3= (const float*)d_in[26], *bnb3= (const float*)d_in[27];
    const float* Wx3 = (const float*)d_in[28], *bx3 = (const float*)d_in[29];
    const float* W1 = (const float*)d_in[30], *b1 = (const float*)d_in[31];
    const float* W2 = (const float*)d_in[32], *b2 = (const float*)d_in[33];
    const float* W3 = (const float*)d_in[34], *b3 = (const float*)d_in[35];
    const float* W4 = (const float*)d_in[36], *b4 = (const float*)d_in[37];
    float* out = (float*)d_out;

    const int N = NNODE;
    char* base = (char*)d_ws;
    size_t off = 0;
    auto alloc = [&](size_t bytes) -> void* {
        void* p = base + off;
        off = (off + bytes + 255) & ~(size_t)255;
        return p;
    };
    // X: one buffer reused as X1 (ld512) -> X2 (ld1664) -> X3 (ld1536); live ranges disjoint
    unsigned short* Xh = (unsigned short*)alloc((size_t)N * 1664 * 2);
    unsigned short* Xl = (unsigned short*)alloc((size_t)N * 1664 * 2);
    float* H2   = (float*)alloc((size_t)N * 832 * 4);          // also dm-tmp before L1
    unsigned short* uh = (unsigned short*)alloc((size_t)N * 384 * 2);
    unsigned short* ul = (unsigned short*)alloc((size_t)N * 384 * 2);
    float* h3b  = (float*)alloc((size_t)N * 192 * 4);
    float* d2f  = (float*)alloc((size_t)N * 32 * 4);
    float* part = (float*)alloc((size_t)128 * 384 * 4);
    float* scale= (float*)alloc(384 * 4);
    float* shift= (float*)alloc(384 * 4);
    float* bias2= (float*)alloc(384 * 4);
    float* biasH1 = (float*)alloc(256 * 4);
    float* biasH2 = (float*)alloc(832 * 4);
    float* biasH3 = (float*)alloc(768 * 4);
    float* nm   = (float*)alloc((size_t)N * 4);
    float* gbuf = (float*)alloc((size_t)N * 4);
    float* smp  = (float*)alloc(64 * 8 * 2 * 4);
    float* smz  = (float*)alloc(64 * 2 * 4);
    auto aw = [&](size_t elems) -> unsigned short* { return (unsigned short*)alloc(elems * 2); };
    unsigned short *BWm1h = aw(256 * 128),   *BWm1l = aw(256 * 128);
    unsigned short *BWu1h = aw(384 * 512),   *BWu1l = aw(384 * 512);
    unsigned short *BWx1h = aw(384 * 384),   *BWx1l = aw(384 * 384);
    unsigned short *BWm2h = aw(896 * 448),   *BWm2l = aw(896 * 448);
    unsigned short *BWu2h = aw(384 * 1664),  *BWu2l = aw(384 * 1664);
    unsigned short *BWx2h = aw(384 * 384),   *BWx2l = aw(384 * 384);
    unsigned short *BWm3h = aw(768 * 384),   *BWm3l = aw(768 * 384);
    unsigned short *BWu3h = aw(256 * 1536),  *BWu3l = aw(256 * 1536);
    unsigned short *BWx3h = aw(256 * 192),   *BWx3l = aw(256 * 192);

    auto gp = [](size_t n) { return dim3((unsigned)((n + 255) / 256)); };

    // ---- weight prep (independent) ----
    prep_bt<<<gp(128 * 128), 256, 0, stream>>>(Wm1,             BWm1h,             BWm1l,             128, 128, 128, 128);
    prep_bt<<<gp(128 * 128), 256, 0, stream>>>(Wm1 + 128 * 128, BWm1h + 128 * 128, BWm1l + 128 * 128, 128, 128, 128, 128);
    prep_wu<<<gp(384 * 512), 256, 0, stream>>>(Wu1, BWu1h, BWu1l, 128, 384, 384);
    prep_bt<<<gp(416 * 448), 256, 0, stream>>>(Wm2,             BWm2h,             BWm2l,             416, 416, 448, 416);
    prep_bt<<<gp(480 * 448), 256, 0, stream>>>(Wm2 + 416 * 416, BWm2h + 416 * 448, BWm2l + 416 * 448, 416, 416, 448, 480);
    prep_wu<<<gp(384 * 1664), 256, 0, stream>>>(Wu2, BWu2h, BWu2l, 416, 384, 384);
    prep_bt<<<gp(384 * 384), 256, 0, stream>>>(Wm3,             BWm3h,             BWm3l,             384, 384, 384, 384);
    prep_bt<<<gp(384 * 384), 256, 0, stream>>>(Wm3 + 384 * 384, BWm3h + 384 * 384, BWm3l + 384 * 384, 384, 384, 384, 384);
    prep_wu<<<gp(256 * 1536), 256, 0, stream>>>(Wu3, BWu3h, BWu3l, 384, 192, 256);
    prep_biasH<<<gp(256), 256, 0, stream>>>(bm1, biasH1, 128);
    prep_biasH<<<gp(832), 256, 0, stream>>>(bm2, biasH2, 416);
    prep_biasH<<<gp(768), 256, 0, stream>>>(bm3, biasH3, 384);

    // ---- ns -> X1 h-part (ld 512, off 0) ----
    csplit_k<<<gp((size_t)N * 128), 256, 0, stream>>>(ns, 128, 128, Xh, Xl, 512, 0);

    // ---- d2 = (dm@W1+b1)@W2+b2 (fp32; H2 as tmp [N,64]) ----
    gemm_k<<<dim3(1, 128), 256, 0, stream>>>(dm, W1, H2, 64, 256, b1);
    gemm_k<<<dim3(1, 128), 256, 0, stream>>>(H2, W2, d2f, 32, 64, b2);

    // ================= layer 1 (cin=128, X ld 512) =================
    mgemm3<0, 0><<<dim3(128, 2), 256, 0, stream>>>(Xh, Xl, 512, 128, BWm1h, BWm1l, 128,
                                                   H2, nullptr, nullptr, 256, 256, biasH1);
    agg2_k<<<dim3(64, 2, 4), 256, 0, stream>>>(H2, es, src, Wm1 + 2 * 128 * 128, Xh, Xl, 128, 256, 512, 128);
    mgemm3<0, 1><<<dim3(128, 3), 256, 0, stream>>>(Xh, Xl, 512, 512, BWu1h, BWu1l, 512,
                                                   nullptr, uh, ul, 384, 384, bu1);
    bnstats1s_k<<<64, 384, 0, stream>>>(uh, ul, part, 384);
    bnstats2_k<<<1, 384, 0, stream>>>(part, bng1, bnb1, scale, shift, 384);
    prep_wx<<<gp(384 * 384), 256, 0, stream>>>(Wx1, scale, BWx1h, BWx1l, 384, 384, 384, 384);
    bias2p_k<<<384, 256, 0, stream>>>(Wx1, bx1, shift, bias2, 384, 384);
    mgemm3<1, 1><<<dim3(128, 3), 256, 0, stream>>>(uh, ul, 384, 384, BWx1h, BWx1l, 384,
                                                   nullptr, Xh, Xl, 1664, 384, bias2);  // h2a -> X2[0:384)
    csplit_k<<<gp((size_t)N * 32), 256, 0, stream>>>(d2f, 32, 32, Xh, Xl, 1664, 384);   // d2 -> X2[384:416)

    // ================= layer 2 (cin=416, X ld 1664) =================
    mgemm3<0, 0><<<dim3(128, 7), 256, 0, stream>>>(Xh, Xl, 1664, 416, BWm2h, BWm2l, 448,
                                                   H2, nullptr, nullptr, 832, 832, biasH2);
    agg2_k<<<dim3(64, 7, 4), 256, 0, stream>>>(H2, es, src, Wm2 + 2 * 416 * 416, Xh, Xl, 416, 832, 1664, 416);
    mgemm3<0, 1><<<dim3(128, 3), 256, 0, stream>>>(Xh, Xl, 1664, 1664, BWu2h, BWu2l, 1664,
                                                   nullptr, uh, ul, 384, 384, bu2);
    bnstats1s_k<<<64, 384, 0, stream>>>(uh, ul, part, 384);
    bnstats2_k<<<1, 384, 0, stream>>>(part, bng2, bnb2, scale, shift, 384);
    prep_wx<<<gp(384 * 384), 256, 0, stream>>>(Wx2, scale, BWx2h, BWx2l, 384, 384, 384, 384);
    bias2p_k<<<384, 256, 0, stream>>>(Wx2, bx2, shift, bias2, 384, 384);
    mgemm3<1, 1><<<dim3(128, 3), 256, 0, stream>>>(uh, ul, 384, 384, BWx2h, BWx2l, 384,
                                                   nullptr, Xh, Xl, 1536, 384, bias2);  // h3-in -> X3[0:384)

    // ================= layer 3 (cin=384, X ld 1536) =================
    mgemm3<0, 0><<<dim3(128, 6), 256, 0, stream>>>(Xh, Xl, 1536, 384, BWm3h, BWm3l, 384,
                                                   H2, nullptr, nullptr, 768, 768, biasH3);
    agg2_k<<<dim3(64, 6, 4), 256, 0, stream>>>(H2, es, src, Wm3 + 2 * 384 * 384, Xh, Xl, 384, 768, 1536, 384);
    mgemm3<0, 1><<<dim3(128, 2), 256, 0, stream>>>(Xh, Xl, 1536, 1536, BWu3h, BWu3l, 1536,
                                                   nullptr, uh, ul, 192, 192, bu3);
    bnstats1s_k<<<64, 384, 0, stream>>>(uh, ul, part, 192);
    bnstats2_k<<<1, 384, 0, stream>>>(part, bng3, bnb3, scale, shift, 192);
    prep_wx<<<gp(256 * 192), 256, 0, stream>>>(Wx3, scale, BWx3h, BWx3l, 192, 192, 192, 256);
    bias2p_k<<<192, 256, 0, stream>>>(Wx3, bx3, shift, bias2, 192, 192);
    mgemm3<2, 0><<<dim3(128, 2), 256, 0, stream>>>(uh, ul, 192, 192, BWx3h, BWx3l, 192,
                                                   h3b, nullptr, nullptr, 192, 192, bias2);

    // ---- head ----
    rowmax_k<<<N / 4, 256, 0, stream>>>(h3b, nm);
    g_k<<<64, 256, 0, stream>>>(nm, W3, b3, W4, b4, gbuf);
    sm1_k<<<dim3(64, 8), 256, 0, stream>>>(mask, gbuf, h3b, smp);
    sm2_k<<<1, 64, 0, stream>>>(smp, smz);
    sm3_k<<<dim3(64, 8), 256, 0, stream>>>(mask, gbuf, h3b, smz, out);
}

// Round 5
// 678.332 us; speedup vs baseline: 1.4199x; 1.4199x over previous
//
#include <hip/hip_runtime.h>
#include <hip/hip_bf16.h>

#define NNODE 16384

typedef short v8s __attribute__((ext_vector_type(8)));
typedef float v4f __attribute__((ext_vector_type(4)));

__device__ __forceinline__ unsigned short f2bf(float v) {
    unsigned u = __float_as_uint(v);
    unsigned r = (u + 0x7FFF + ((u >> 16) & 1)) >> 16;
    return (unsigned short)r;
}
__device__ __forceinline__ float bf2f(unsigned short s) {
    return __uint_as_float(((unsigned)s) << 16);
}

// ======================= split-bf16 MFMA GEMM v4 (A+B in LDS, BMx64 tile) ==========
// C[16384, Ncol] = epi( A @ B + bias ). A pre-split bf16 planes [16384][ldA].
// B pre-split/transposed [Npad][Kpad], Kpad=ceil64(K), zero-padded.
// Tile BMx64 (BM=128 or 64), 4 waves (2x2), wave tile (BM/2)x32.
// LDS XOR swizzle (row&7)<<4 on both operands. 3-term split: Ah*Bh + Al*Bh + Ah*Bl.
// OUT: 0 = f32 C, 1 = split bf16 planes Ch/Cl.
template<int EPI, int OUT, int BM>
__global__ __launch_bounds__(256, 3)
void mgemm4(const unsigned short* __restrict__ Ah, const unsigned short* __restrict__ Al,
            int ldA, int K,
            const unsigned short* __restrict__ Bh, const unsigned short* __restrict__ Bl,
            int Kpad,
            float* __restrict__ Cf, unsigned short* __restrict__ Ch, unsigned short* __restrict__ Cl,
            int ldC, int Ncol, const float* __restrict__ bias)
{
    constexpr int MF = BM / 32;          // m-frags per wave
    __shared__ __align__(16) unsigned short AhS[BM * 64];
    __shared__ __align__(16) unsigned short AlS[BM * 64];
    __shared__ __align__(16) unsigned short BhS[64 * 64];
    __shared__ __align__(16) unsigned short BlS[64 * 64];
    const int bm = blockIdx.x * BM;
    const int bn = blockIdx.y * 64;
    const int tid = threadIdx.x;
    const int lane = tid & 63, wid = tid >> 6;
    const int wm = wid >> 1, wn = wid & 1;
    const int r16 = lane & 15, q = lane >> 4;
    v4f acc[MF][2];
#pragma unroll
    for (int i = 0; i < MF; i++)
#pragma unroll
        for (int j = 0; j < 2; j++) acc[i][j] = (v4f){0.f, 0.f, 0.f, 0.f};

    const int srow = tid >> 3;            // 0..31 per 256-chunk group
    const int sc8  = tid & 7;             // 16B chunk in row
    const int nK = (K + 63) >> 6;
    for (int s = 0; s < nK; s++) {
        const int k0 = s << 6;
        // ---- stage A tile: BM rows x 64 k, both planes, coalesced ----
#pragma unroll
        for (int p = 0; p < BM / 32; p++) {
            int row = p * 32 + srow;
            size_t go = (size_t)(bm + row) * ldA + k0 + sc8 * 8;
            v8s hv = *(const v8s*)(const void*)(Ah + go);
            v8s lv = *(const v8s*)(const void*)(Al + go);
            int bo = row * 128 + ((sc8 * 16) ^ ((row & 7) << 4));
            *(v8s*)(void*)((char*)AhS + bo) = hv;
            *(v8s*)(void*)((char*)AlS + bo) = lv;
        }
        // ---- stage B tile: 64 cols x 64 k, both planes, coalesced ----
#pragma unroll
        for (int p = 0; p < 2; p++) {
            int row = p * 32 + srow;      // col index within tile
            size_t go = (size_t)(bn + row) * Kpad + k0 + sc8 * 8;
            v8s hv = *(const v8s*)(const void*)(Bh + go);
            v8s lv = *(const v8s*)(const void*)(Bl + go);
            int bo = row * 128 + ((sc8 * 16) ^ ((row & 7) << 4));
            *(v8s*)(void*)((char*)BhS + bo) = hv;
            *(v8s*)(void*)((char*)BlS + bo) = lv;
        }
        __syncthreads();
        // ---- compute ----
#pragma unroll
        for (int kc = 0; kc < 2; kc++) {
            v8s bh[2], bl[2];
#pragma unroll
            for (int nf = 0; nf < 2; nf++) {
                int bcol = wn * 32 + nf * 16 + r16;
                int bo = bcol * 128 + (((kc * 64) + q * 16) ^ ((bcol & 7) << 4));
                bh[nf] = *(const v8s*)(const void*)((const char*)BhS + bo);
                bl[nf] = *(const v8s*)(const void*)((const char*)BlS + bo);
            }
#pragma unroll
            for (int mf = 0; mf < MF; mf++) {
                int arow = wm * (BM / 2) + mf * 16 + r16;
                int ao = arow * 128 + (((kc * 64) + q * 16) ^ ((arow & 7) << 4));
                v8s ah = *(const v8s*)(const void*)((const char*)AhS + ao);
                v8s al = *(const v8s*)(const void*)((const char*)AlS + ao);
#pragma unroll
                for (int nf = 0; nf < 2; nf++) {
                    acc[mf][nf] = __builtin_amdgcn_mfma_f32_16x16x32_bf16(ah, bh[nf], acc[mf][nf], 0, 0, 0);
                    acc[mf][nf] = __builtin_amdgcn_mfma_f32_16x16x32_bf16(al, bh[nf], acc[mf][nf], 0, 0, 0);
                    acc[mf][nf] = __builtin_amdgcn_mfma_f32_16x16x32_bf16(ah, bl[nf], acc[mf][nf], 0, 0, 0);
                }
            }
        }
        __syncthreads();
    }
    // ---- epilogue ----
#pragma unroll
    for (int mf = 0; mf < MF; mf++)
#pragma unroll
        for (int nf = 0; nf < 2; nf++) {
            int col = bn + wn * 32 + nf * 16 + r16;
            if (col < Ncol) {
                float bv = bias ? bias[col] : 0.f;
#pragma unroll
                for (int r = 0; r < 4; r++) {
                    int row = bm + wm * (BM / 2) + mf * 16 + q * 4 + r;
                    float v = acc[mf][nf][r] + bv;
                    if (EPI == 1) v = fmaxf(v, 0.f);
                    if (EPI == 2) v = (v > 0.f) ? v : 0.01f * v;
                    size_t o = (size_t)row * ldC + col;
                    if (OUT == 0) {
                        Cf[o] = v;
                    } else {
                        unsigned short h = f2bf(v);
                        Ch[o] = h;
                        Cl[o] = f2bf(v - bf2f(h));
                    }
                }
            }
        }
}

// ======================= weight preps =======================
__global__ void prep_bt(const float* __restrict__ W, unsigned short* __restrict__ Bh,
                        unsigned short* __restrict__ Bl, int K, int N, int Kpad, int Npad)
{
    int idx = blockIdx.x * 256 + threadIdx.x;
    if (idx >= Npad * Kpad) return;
    int n = idx / Kpad, k = idx % Kpad;
    float v = (n < N && k < K) ? W[(size_t)k * N + n] : 0.f;
    unsigned short h = f2bf(v);
    Bh[idx] = h;
    Bl[idx] = f2bf(v - bf2f(h));
}

// Wu fold: source [5cin, cout]; X row layout [h(cin) | sum | max | std] -> K = 4cin
__global__ void prep_wu(const float* __restrict__ Wu, unsigned short* __restrict__ Bh,
                        unsigned short* __restrict__ Bl, int cin, int cout, int Npad)
{
    int Kpad = 4 * cin;
    int idx = blockIdx.x * 256 + threadIdx.x;
    if (idx >= Npad * Kpad) return;
    int n = idx / Kpad, k = idx % Kpad;
    float v = 0.f;
    if (n < cout) {
        int qq = k / cin, r = k - qq * cin;
        if (qq == 0)      v = Wu[(size_t)r * cout + n];
        else if (qq == 1) v = Wu[(size_t)(cin + r) * cout + n] * 0.125f + Wu[(size_t)(3 * cin + r) * cout + n];
        else if (qq == 2) v = Wu[(size_t)(2 * cin + r) * cout + n];
        else              v = Wu[(size_t)(4 * cin + r) * cout + n];
    }
    unsigned short h = f2bf(v);
    Bh[idx] = h;
    Bl[idx] = f2bf(v - bf2f(h));
}

// Wx scaled by BN scale: B[n][k] = Wx[k][n]*scale[k]
__global__ void prep_wx(const float* __restrict__ Wx, const float* __restrict__ scale,
                        unsigned short* __restrict__ Bh, unsigned short* __restrict__ Bl,
                        int K, int N, int Kpad, int Npad)
{
    int idx = blockIdx.x * 256 + threadIdx.x;
    if (idx >= Npad * Kpad) return;
    int n = idx / Kpad, k = idx % Kpad;
    float v = (n < N && k < K) ? Wx[(size_t)k * N + n] * scale[k] : 0.f;
    unsigned short h = f2bf(v);
    Bh[idx] = h;
    Bl[idx] = f2bf(v - bf2f(h));
}

// bias2[n] = bx[n] + sum_k shift[k]*Wx[k][n]   (one block per n)
__global__ __launch_bounds__(256) void bias2p_k(const float* __restrict__ Wx,
    const float* __restrict__ bx, const float* __restrict__ shift,
    float* __restrict__ bias2, int K, int N)
{
    int n = blockIdx.x, tid = threadIdx.x;
    float s = 0.f;
    for (int k = tid; k < K; k += 256) s = fmaf(shift[k], Wx[(size_t)k * N + n], s);
    __shared__ float red[256];
    red[tid] = s; __syncthreads();
    for (int st = 128; st > 0; st >>= 1) { if (tid < st) red[tid] += red[tid + st]; __syncthreads(); }
    if (tid == 0) bias2[n] = red[0] + bx[n];
}

// Wm bias for H2 columns: [0]*cin ++ bm
__global__ void prep_biasH(const float* __restrict__ bm, float* __restrict__ biasH, int cin)
{
    int i = blockIdx.x * 256 + threadIdx.x;
    if (i < 2 * cin) biasH[i] = (i < cin) ? 0.f : bm[i - cin];
}

// f32 [16384, w] (ld ldS) -> split planes at column offset offX
__global__ void csplit_k(const float* __restrict__ src, int ldS, int w,
                         unsigned short* __restrict__ Xh, unsigned short* __restrict__ Xl,
                         int ldX, int offX)
{
    int idx = blockIdx.x * 256 + threadIdx.x;
    if (idx >= NNODE * w) return;
    int rrow = idx / w, c = idx - rrow * w;
    float v = src[(size_t)rrow * ldS + c];
    unsigned short h = f2bf(v);
    size_t o = (size_t)rrow * ldX + offX + c;
    Xh[o] = h;
    Xl[o] = f2bf(v - bf2f(h));
}

// ======================= fp32 GEMM (small d2 path) =======================
__global__ __launch_bounds__(256)
void gemm_k(const float* __restrict__ A, const float* __restrict__ Bw,
            float* __restrict__ C, int Ncol, int K, const float* __restrict__ bias)
{
    __shared__ float As[16][128];
    __shared__ float Bs[16][64];
    const int bm = blockIdx.y * 128;
    const int bn = blockIdx.x * 64;
    const int tid = threadIdx.x;
    const int tx = tid & 15, ty = tid >> 4;
    float acc[8][4];
#pragma unroll
    for (int i = 0; i < 8; i++)
#pragma unroll
        for (int j = 0; j < 4; j++) acc[i][j] = 0.f;

    for (int k0 = 0; k0 < K; k0 += 16) {
#pragma unroll
        for (int i = 0; i < 2; i++) {
            int idx = tid * 2 + i;
            int row = idx >> 2;
            int k4  = (idx & 3) << 2;
            const float* ap = A + (size_t)(bm + row) * K + k0 + k4;
            float4 v = *reinterpret_cast<const float4*>(ap);
            As[k4 + 0][row] = v.x;
            As[k4 + 1][row] = v.y;
            As[k4 + 2][row] = v.z;
            As[k4 + 3][row] = v.w;
        }
        {
            int row = tid >> 4;
            int c4  = (tid & 15) << 2;
            int gn  = bn + c4;
            float4 v;
            if (gn + 3 < Ncol) {
                v = *reinterpret_cast<const float4*>(Bw + (size_t)(k0 + row) * Ncol + gn);
            } else {
                float t0 = (gn + 0 < Ncol) ? Bw[(size_t)(k0 + row) * Ncol + gn + 0] : 0.f;
                float t1 = (gn + 1 < Ncol) ? Bw[(size_t)(k0 + row) * Ncol + gn + 1] : 0.f;
                float t2 = (gn + 2 < Ncol) ? Bw[(size_t)(k0 + row) * Ncol + gn + 2] : 0.f;
                float t3 = (gn + 3 < Ncol) ? Bw[(size_t)(k0 + row) * Ncol + gn + 3] : 0.f;
                v = make_float4(t0, t1, t2, t3);
            }
            *reinterpret_cast<float4*>(&Bs[row][c4]) = v;
        }
        __syncthreads();
#pragma unroll
        for (int kk = 0; kk < 16; kk++) {
            float a0[8], b0[4];
#pragma unroll
            for (int i = 0; i < 8; i++) a0[i] = As[kk][ty * 8 + i];
#pragma unroll
            for (int j = 0; j < 4; j++) b0[j] = Bs[kk][tx * 4 + j];
#pragma unroll
            for (int i = 0; i < 8; i++)
#pragma unroll
                for (int j = 0; j < 4; j++) acc[i][j] = fmaf(a0[i], b0[j], acc[i][j]);
        }
        __syncthreads();
    }
#pragma unroll
    for (int i = 0; i < 8; i++) {
        int r = bm + ty * 8 + i;
#pragma unroll
        for (int j = 0; j < 4; j++) {
            int c = bn + tx * 4 + j;
            if (c < Ncol) C[(size_t)r * Ncol + c] = acc[i][j] + (bias ? bias[c] : 0.f);
        }
    }
}

// ======================= PNA aggregation (split-bf16 output into X) =======================
__global__ __launch_bounds__(256)
void agg2_k(const float* __restrict__ H2, const float* __restrict__ es,
            const int* __restrict__ src, const float* __restrict__ Wme,
            unsigned short* __restrict__ Xh, unsigned short* __restrict__ Xl,
            int cin, int ldH, int ldX, int offX)
{
    const int g = blockIdx.x;
    const int c0 = blockIdx.y * 64;
    const int qz = blockIdx.z;
    const int tid = threadIdx.x;
    const int nl = tid >> 6, c = tid & 63;
    const int cc = c0 + c;
    const bool act = cc < cin;
    __shared__ float esl[4][128];
    __shared__ int srcl[512];
    {
        int e0 = g * 2048 + qz * 512;
        for (int i = tid; i < 512; i += 256) srcl[i] = src[e0 + i] - g * 256;
    }
    float wreg[16];
#pragma unroll
    for (int j = 0; j < 16; j++) wreg[j] = act ? Wme[j * cin + cc] : 0.f;
    __syncthreads();
    const float* Hsrc = H2 + (size_t)(g * 256) * ldH + c0;
    const float* Hdst = H2 + (size_t)(g * 256) * ldH + cin + c0;
    for (int i = 0; i < 16; i++) {
        const int vl = qz * 64 + i * 4 + nl;
        {
            const float* ep = es + (size_t)(g * 256 + vl) * 128;
            esl[nl][c] = ep[c];
            esl[nl][64 + c] = ep[64 + c];
        }
        __syncthreads();
        if (act) {
            float hd = Hdst[(size_t)vl * ldH + c];
            float sum = 0.f, sq = 0.f, mx = -INFINITY;
#pragma unroll
            for (int e = 0; e < 8; e++) {
                int sl = srcl[(i * 4 + nl) * 8 + e];
                float m = hd + Hsrc[(size_t)sl * ldH + c];
                float4 e0 = *(const float4*)&esl[nl][e * 16 + 0];
                float4 e1 = *(const float4*)&esl[nl][e * 16 + 4];
                float4 e2 = *(const float4*)&esl[nl][e * 16 + 8];
                float4 e3 = *(const float4*)&esl[nl][e * 16 + 12];
                m = fmaf(e0.x, wreg[0], m);  m = fmaf(e0.y, wreg[1], m);
                m = fmaf(e0.z, wreg[2], m);  m = fmaf(e0.w, wreg[3], m);
                m = fmaf(e1.x, wreg[4], m);  m = fmaf(e1.y, wreg[5], m);
                m = fmaf(e1.z, wreg[6], m);  m = fmaf(e1.w, wreg[7], m);
                m = fmaf(e2.x, wreg[8], m);  m = fmaf(e2.y, wreg[9], m);
                m = fmaf(e2.z, wreg[10], m); m = fmaf(e2.w, wreg[11], m);
                m = fmaf(e3.x, wreg[12], m); m = fmaf(e3.y, wreg[13], m);
                m = fmaf(e3.z, wreg[14], m); m = fmaf(e3.w, wreg[15], m);
                sum += m;
                sq = fmaf(m, m, sq);
                mx = fmaxf(mx, m);
            }
            float mean = sum * 0.125f, msq = sq * 0.125f;
            float stdv = sqrtf(fmaxf(msq - mean * mean, 0.f) + 1e-30f);
            size_t o = (size_t)(g * 256 + vl) * ldX + offX + cc;
            unsigned short h;
            h = f2bf(sum);  Xh[o] = h;            Xl[o] = f2bf(sum - bf2f(h));
            h = f2bf(mx);   Xh[o + cin] = h;      Xl[o + cin] = f2bf(mx - bf2f(h));
            h = f2bf(stdv); Xh[o + 2 * cin] = h;  Xl[o + 2 * cin] = f2bf(stdv - bf2f(h));
        }
        __syncthreads();
    }
}

// ======================= BatchNorm stats (deterministic, split-bf16 input) ===========
__global__ void bnstats1s_k(const unsigned short* __restrict__ uh, const unsigned short* __restrict__ ul,
                            float* __restrict__ part, int cout)
{
    int c = threadIdx.x;
    if (c >= cout) return;
    int r0 = blockIdx.x * 256;
    float s = 0.f, q = 0.f;
    for (int r = r0; r < r0 + 256; r++) {
        size_t o = (size_t)r * cout + c;
        float v = bf2f(uh[o]) + bf2f(ul[o]);
        s += v;
        q = fmaf(v, v, q);
    }
    part[(size_t)blockIdx.x * cout + c] = s;
    part[(size_t)(64 + blockIdx.x) * cout + c] = q;
}

__global__ void bnstats2_k(const float* __restrict__ part, const float* __restrict__ bng,
                           const float* __restrict__ bnb, float* __restrict__ scale,
                           float* __restrict__ shift, int cout)
{
    int c = threadIdx.x;
    if (c >= cout) return;
    float s = 0.f, q = 0.f;
    for (int b = 0; b < 64; b++) { s += part[(size_t)b * cout + c]; q += part[(size_t)(64 + b) * cout + c]; }
    float mean = s / 16384.f;
    float var  = q / 16384.f - mean * mean;
    float sc   = bng[c] / sqrtf(var + 1e-5f);
    scale[c] = sc;
    shift[c] = bnb[c] - mean * sc;
}

// ======================= head =======================
__global__ void rowmax_k(const float* __restrict__ h3, float* __restrict__ nm)
{
    int wave = threadIdx.x >> 6;
    int lane = threadIdx.x & 63;
    int node = blockIdx.x * 4 + wave;
    const float* row = h3 + (size_t)node * 192;
    float m = -INFINITY;
    for (int t = lane; t < 192; t += 64) m = fmaxf(m, row[t]);
#pragma unroll
    for (int off = 32; off > 0; off >>= 1) m = fmaxf(m, __shfl_down(m, off, 64));
    if (lane == 0) nm[node] = m;
}

__global__ __launch_bounds__(256) void g_k(const float* __restrict__ nm,
    const float* __restrict__ W3, const float* __restrict__ b3,
    const float* __restrict__ W4, const float* __restrict__ b4,
    float* __restrict__ g)
{
    __shared__ float row[256];
    __shared__ float t1[64];
    int b = blockIdx.x, tid = threadIdx.x;
    row[tid] = nm[b * 256 + tid];
    __syncthreads();
    if (tid < 64) {
        float a = b3[tid];
        for (int k = 0; k < 256; k++) a = fmaf(row[k], W3[k * 64 + tid], a);
        t1[tid] = fmaxf(a, 0.f);
    }
    __syncthreads();
    float a = b4[tid];
    for (int j = 0; j < 64; j++) a = fmaf(t1[j], W4[j * 256 + tid], a);
    g[b * 256 + tid] = 1.f / (1.f + expf(-a));
}

// ======================= masked softmax (parallel, 2-pass) =======================
__global__ __launch_bounds__(256) void sm1_k(const float* __restrict__ mask,
    const float* __restrict__ g, const float* __restrict__ h3, float* __restrict__ part)
{
    int b = blockIdx.x, s = blockIdx.y, tid = threadIdx.x;
    float l[24];
#pragma unroll
    for (int t = 0; t < 24; t++) {
        int i = s * 6144 + t * 256 + tid;
        size_t idx = (size_t)b * 49152 + i;
        float mk = mask[idx];
        l[t] = (mk == 0.f) ? -1e5f : g[b * 256 + i / 192] * h3[idx];
    }
    float m = -INFINITY;
#pragma unroll
    for (int t = 0; t < 24; t++) m = fmaxf(m, l[t]);
    __shared__ float red[256];
    red[tid] = m; __syncthreads();
    for (int st = 128; st > 0; st >>= 1) { if (tid < st) red[tid] = fmaxf(red[tid], red[tid + st]); __syncthreads(); }
    m = red[0]; __syncthreads();
    float z = 0.f;
#pragma unroll
    for (int t = 0; t < 24; t++) z += expf(l[t] - m);
    red[tid] = z; __syncthreads();
    for (int st = 128; st > 0; st >>= 1) { if (tid < st) red[tid] += red[tid + st]; __syncthreads(); }
    if (tid == 0) { part[(b * 8 + s) * 2] = m; part[(b * 8 + s) * 2 + 1] = red[0]; }
}

__global__ void sm2_k(const float* __restrict__ part, float* __restrict__ mz)
{
    int b = threadIdx.x;
    if (b >= 64) return;
    float M = -INFINITY;
    for (int s = 0; s < 8; s++) M = fmaxf(M, part[(b * 8 + s) * 2]);
    float Z = 0.f;
    for (int s = 0; s < 8; s++) Z += part[(b * 8 + s) * 2 + 1] * expf(part[(b * 8 + s) * 2] - M);
    mz[b * 2] = M;
    mz[b * 2 + 1] = 1.f / Z;
}

__global__ __launch_bounds__(256) void sm3_k(const float* __restrict__ mask,
    const float* __restrict__ g, const float* __restrict__ h3,
    const float* __restrict__ mz, float* __restrict__ out)
{
    int b = blockIdx.x, s = blockIdx.y, tid = threadIdx.x;
    float M = mz[b * 2], invZ = mz[b * 2 + 1];
#pragma unroll
    for (int t = 0; t < 24; t++) {
        int i = s * 6144 + t * 256 + tid;
        size_t idx = (size_t)b * 49152 + i;
        float mk = mask[idx];
        float v = (mk == 0.f) ? -1e5f : g[b * 256 + i / 192] * h3[idx];
        out[idx] = expf(v - M) * invZ;
    }
}

// ======================= launcher =======================
extern "C" void kernel_launch(void* const* d_in, const int* in_sizes, int n_in,
                              void* d_out, int out_size, void* d_ws, size_t ws_size,
                              hipStream_t stream)
{
    const float* ns   = (const float*)d_in[0];
    const float* es   = (const float*)d_in[1];
    const float* dm   = (const float*)d_in[2];
    const float* mask = (const float*)d_in[3];
    const int*   src  = (const int*)d_in[4];
    const float* Wm1 = (const float*)d_in[6],  *bm1 = (const float*)d_in[7];
    const float* Wu1 = (const float*)d_in[8],  *bu1 = (const float*)d_in[9];
    const float* bng1= (const float*)d_in[10], *bnb1= (const float*)d_in[11];
    const float* Wx1 = (const float*)d_in[12], *bx1 = (const float*)d_in[13];
    const float* Wm2 = (const float*)d_in[14], *bm2 = (const float*)d_in[15];
    const float* Wu2 = (const float*)d_in[16], *bu2 = (const float*)d_in[17];
    const float* bng2= (const float*)d_in[18], *bnb2= (const float*)d_in[19];
    const float* Wx2 = (const float*)d_in[20], *bx2 = (const float*)d_in[21];
    const float* Wm3 = (const float*)d_in[22], *bm3 = (const float*)d_in[23];
    const float* Wu3 = (const float*)d_in[24], *bu3 = (const float*)d_in[25];
    const float* bng3= (const float*)d_in[26], *bnb3= (const float*)d_in[27];
    const float* Wx3 = (const float*)d_in[28], *bx3 = (const float*)d_in[29];
    const float* W1 = (const float*)d_in[30], *b1 = (const float*)d_in[31];
    const float* W2 = (const float*)d_in[32], *b2 = (const float*)d_in[33];
    const float* W3 = (const float*)d_in[34], *b3 = (const float*)d_in[35];
    const float* W4 = (const float*)d_in[36], *b4 = (const float*)d_in[37];
    float* out = (float*)d_out;

    const int N = NNODE;
    char* base = (char*)d_ws;
    size_t off = 0;
    auto alloc = [&](size_t bytes) -> void* {
        void* p = base + off;
        off = (off + bytes + 255) & ~(size_t)255;
        return p;
    };
    // X: one buffer reused as X1 (ld512) -> X2 (ld1664) -> X3 (ld1536); live ranges disjoint
    unsigned short* Xh = (unsigned short*)alloc((size_t)N * 1664 * 2);
    unsigned short* Xl = (unsigned short*)alloc((size_t)N * 1664 * 2);
    float* H2   = (float*)alloc((size_t)N * 832 * 4);          // also dm-tmp before L1
    unsigned short* uh = (unsigned short*)alloc((size_t)N * 384 * 2);
    unsigned short* ul = (unsigned short*)alloc((size_t)N * 384 * 2);
    float* h3b  = (float*)alloc((size_t)N * 192 * 4);
    float* d2f  = (float*)alloc((size_t)N * 32 * 4);
    float* part = (float*)alloc((size_t)128 * 384 * 4);
    float* scale= (float*)alloc(384 * 4);
    float* shift= (float*)alloc(384 * 4);
    float* bias2= (float*)alloc(384 * 4);
    float* biasH1 = (float*)alloc(256 * 4);
    float* biasH2 = (float*)alloc(832 * 4);
    float* biasH3 = (float*)alloc(768 * 4);
    float* nm   = (float*)alloc((size_t)N * 4);
    float* gbuf = (float*)alloc((size_t)N * 4);
    float* smp  = (float*)alloc(64 * 8 * 2 * 4);
    float* smz  = (float*)alloc(64 * 2 * 4);
    auto aw = [&](size_t elems) -> unsigned short* { return (unsigned short*)alloc(elems * 2); };
    unsigned short *BWm1h = aw(256 * 128),   *BWm1l = aw(256 * 128);
    unsigned short *BWu1h = aw(384 * 512),   *BWu1l = aw(384 * 512);
    unsigned short *BWx1h = aw(384 * 384),   *BWx1l = aw(384 * 384);
    unsigned short *BWm2h = aw(896 * 448),   *BWm2l = aw(896 * 448);
    unsigned short *BWu2h = aw(384 * 1664),  *BWu2l = aw(384 * 1664);
    unsigned short *BWx2h = aw(384 * 384),   *BWx2l = aw(384 * 384);
    unsigned short *BWm3h = aw(768 * 384),   *BWm3l = aw(768 * 384);
    unsigned short *BWu3h = aw(256 * 1536),  *BWu3l = aw(256 * 1536);
    unsigned short *BWx3h = aw(256 * 192),   *BWx3l = aw(256 * 192);

    auto gp = [](size_t n) { return dim3((unsigned)((n + 255) / 256)); };

    // ---- weight prep (independent) ----
    prep_bt<<<gp(128 * 128), 256, 0, stream>>>(Wm1,             BWm1h,             BWm1l,             128, 128, 128, 128);
    prep_bt<<<gp(128 * 128), 256, 0, stream>>>(Wm1 + 128 * 128, BWm1h + 128 * 128, BWm1l + 128 * 128, 128, 128, 128, 128);
    prep_wu<<<gp(384 * 512), 256, 0, stream>>>(Wu1, BWu1h, BWu1l, 128, 384, 384);
    prep_bt<<<gp(416 * 448), 256, 0, stream>>>(Wm2,             BWm2h,             BWm2l,             416, 416, 448, 416);
    prep_bt<<<gp(480 * 448), 256, 0, stream>>>(Wm2 + 416 * 416, BWm2h + 416 * 448, BWm2l + 416 * 448, 416, 416, 448, 480);
    prep_wu<<<gp(384 * 1664), 256, 0, stream>>>(Wu2, BWu2h, BWu2l, 416, 384, 384);
    prep_bt<<<gp(384 * 384), 256, 0, stream>>>(Wm3,             BWm3h,             BWm3l,             384, 384, 384, 384);
    prep_bt<<<gp(384 * 384), 256, 0, stream>>>(Wm3 + 384 * 384, BWm3h + 384 * 384, BWm3l + 384 * 384, 384, 384, 384, 384);
    prep_wu<<<gp(256 * 1536), 256, 0, stream>>>(Wu3, BWu3h, BWu3l, 384, 192, 256);
    prep_biasH<<<gp(256), 256, 0, stream>>>(bm1, biasH1, 128);
    prep_biasH<<<gp(832), 256, 0, stream>>>(bm2, biasH2, 416);
    prep_biasH<<<gp(768), 256, 0, stream>>>(bm3, biasH3, 384);

    // ---- ns -> X1 h-part (ld 512, off 0) ----
    csplit_k<<<gp((size_t)N * 128), 256, 0, stream>>>(ns, 128, 128, Xh, Xl, 512, 0);

    // ---- d2 = (dm@W1+b1)@W2+b2 (fp32; H2 as tmp [N,64]) ----
    gemm_k<<<dim3(1, 128), 256, 0, stream>>>(dm, W1, H2, 64, 256, b1);
    gemm_k<<<dim3(1, 128), 256, 0, stream>>>(H2, W2, d2f, 32, 64, b2);

    // ================= layer 1 (cin=128, X ld 512) =================
    mgemm4<0, 0, 128><<<dim3(128, 4), 256, 0, stream>>>(Xh, Xl, 512, 128, BWm1h, BWm1l, 128,
                                                        H2, nullptr, nullptr, 256, 256, biasH1);
    agg2_k<<<dim3(64, 2, 4), 256, 0, stream>>>(H2, es, src, Wm1 + 2 * 128 * 128, Xh, Xl, 128, 256, 512, 128);
    mgemm4<0, 1, 128><<<dim3(128, 6), 256, 0, stream>>>(Xh, Xl, 512, 512, BWu1h, BWu1l, 512,
                                                        nullptr, uh, ul, 384, 384, bu1);
    bnstats1s_k<<<64, 384, 0, stream>>>(uh, ul, part, 384);
    bnstats2_k<<<1, 384, 0, stream>>>(part, bng1, bnb1, scale, shift, 384);
    prep_wx<<<gp(384 * 384), 256, 0, stream>>>(Wx1, scale, BWx1h, BWx1l, 384, 384, 384, 384);
    bias2p_k<<<384, 256, 0, stream>>>(Wx1, bx1, shift, bias2, 384, 384);
    mgemm4<1, 1, 128><<<dim3(128, 6), 256, 0, stream>>>(uh, ul, 384, 384, BWx1h, BWx1l, 384,
                                                        nullptr, Xh, Xl, 1664, 384, bias2);  // h2a -> X2[0:384)
    csplit_k<<<gp((size_t)N * 32), 256, 0, stream>>>(d2f, 32, 32, Xh, Xl, 1664, 384);        // d2 -> X2[384:416)

    // ================= layer 2 (cin=416, X ld 1664) =================
    mgemm4<0, 0, 128><<<dim3(128, 13), 256, 0, stream>>>(Xh, Xl, 1664, 416, BWm2h, BWm2l, 448,
                                                         H2, nullptr, nullptr, 832, 832, biasH2);
    agg2_k<<<dim3(64, 7, 4), 256, 0, stream>>>(H2, es, src, Wm2 + 2 * 416 * 416, Xh, Xl, 416, 832, 1664, 416);
    mgemm4<0, 1, 128><<<dim3(128, 6), 256, 0, stream>>>(Xh, Xl, 1664, 1664, BWu2h, BWu2l, 1664,
                                                        nullptr, uh, ul, 384, 384, bu2);
    bnstats1s_k<<<64, 384, 0, stream>>>(uh, ul, part, 384);
    bnstats2_k<<<1, 384, 0, stream>>>(part, bng2, bnb2, scale, shift, 384);
    prep_wx<<<gp(384 * 384), 256, 0, stream>>>(Wx2, scale, BWx2h, BWx2l, 384, 384, 384, 384);
    bias2p_k<<<384, 256, 0, stream>>>(Wx2, bx2, shift, bias2, 384, 384);
    mgemm4<1, 1, 128><<<dim3(128, 6), 256, 0, stream>>>(uh, ul, 384, 384, BWx2h, BWx2l, 384,
                                                        nullptr, Xh, Xl, 1536, 384, bias2);  // h3-in -> X3[0:384)

    // ================= layer 3 (cin=384, X ld 1536) =================
    mgemm4<0, 0, 128><<<dim3(128, 12), 256, 0, stream>>>(Xh, Xl, 1536, 384, BWm3h, BWm3l, 384,
                                                         H2, nullptr, nullptr, 768, 768, biasH3);
    agg2_k<<<dim3(64, 6, 4), 256, 0, stream>>>(H2, es, src, Wm3 + 2 * 384 * 384, Xh, Xl, 384, 768, 1536, 384);
    mgemm4<0, 1, 64><<<dim3(256, 3), 256, 0, stream>>>(Xh, Xl, 1536, 1536, BWu3h, BWu3l, 1536,
                                                       nullptr, uh, ul, 192, 192, bu3);
    bnstats1s_k<<<64, 384, 0, stream>>>(uh, ul, part, 192);
    bnstats2_k<<<1, 384, 0, stream>>>(part, bng3, bnb3, scale, shift, 192);
    prep_wx<<<gp(256 * 192), 256, 0, stream>>>(Wx3, scale, BWx3h, BWx3l, 192, 192, 192, 256);
    bias2p_k<<<192, 256, 0, stream>>>(Wx3, bx3, shift, bias2, 192, 192);
    mgemm4<2, 0, 64><<<dim3(256, 3), 256, 0, stream>>>(uh, ul, 192, 192, BWx3h, BWx3l, 192,
                                                       h3b, nullptr, nullptr, 192, 192, bias2);

    // ---- head ----
    rowmax_k<<<N / 4, 256, 0, stream>>>(h3b, nm);
    g_k<<<64, 256, 0, stream>>>(nm, W3, b3, W4, b4, gbuf);
    sm1_k<<<dim3(64, 8), 256, 0, stream>>>(mask, gbuf, h3b, smp);
    sm2_k<<<1, 64, 0, stream>>>(smp, smz);
    sm3_k<<<dim3(64, 8), 256, 0, stream>>>(mask, gbuf, h3b, smz, out);
}